// Round 1
// baseline (5979.078 us; speedup 1.0000x reference)
//
#include <hip/hip_runtime.h>
#include <hip/hip_bf16.h>
#include <math.h>

#define B_ 8
#define S_ 4096
#define D_ 768
#define NH_ 4
#define DH_ 192
#define G_ 4
#define NTOT_ 768   // G_*DH_

typedef __attribute__((ext_vector_type(8))) short short8;
typedef __attribute__((ext_vector_type(4))) float floatx4;

__device__ __forceinline__ short f2bs(float f) {
  union { float f; unsigned u; } v; v.f = f;
  unsigned r = v.u + 0x7FFFu + ((v.u >> 16) & 1u);
  return (short)(r >> 16);
}
__device__ __forceinline__ float bs2f(unsigned short s) {
  union { unsigned u; float f; } v; v.u = ((unsigned)s) << 16;
  return v.f;
}

// ---------------- K0: weights -> bf16, fragment-friendly [hg][o][d] ----------------
__global__ __launch_bounds__(256) void wconv_kernel(
    const float* __restrict__ wf, const float* __restrict__ wi,
    const float* __restrict__ wz, const float* __restrict__ wo,
    short* __restrict__ Wbf)
{
  int idx = blockIdx.x * 256 + threadIdx.x;      // < 16*36864
  int hg = idx / (DH_ * DH_);
  int r  = idx % (DH_ * DH_);
  int h = hg >> 2, g = hg & 3;
  const float* W = (g == 0) ? wf : (g == 1) ? wi : (g == 2) ? wz : wo;
  Wbf[idx] = f2bs(W[(size_t)h * DH_ * DH_ + r]);
}

// ---------------- K1: depthwise causal conv + SiLU; also bf16 copy of x ----------------
__global__ __launch_bounds__(256) void conv_silu_kernel(
    const float* __restrict__ x, const float* __restrict__ cw, const float* __restrict__ cb,
    short* __restrict__ xb, short* __restrict__ xcb)
{
  const int b  = blockIdx.x / (S_ / 64);
  const int s0 = (blockIdx.x % (S_ / 64)) * 64;
  const int tid = threadIdx.x;
  float wv[3][4], bias[3], win[3][3];
  for (int j = 0; j < 3; ++j) {
    int d = tid + j * 256;
    for (int k = 0; k < 4; ++k) wv[j][k] = cw[d * 4 + k];
    bias[j] = cb[d];
    for (int p = 0; p < 3; ++p) {
      int s = s0 - 3 + p;
      win[j][p] = (s >= 0) ? x[((size_t)b * S_ + s) * D_ + d] : 0.f;
    }
  }
  for (int i = 0; i < 64; ++i) {
    size_t base = ((size_t)b * S_ + (s0 + i)) * D_;
    for (int j = 0; j < 3; ++j) {
      int d = tid + j * 256;
      float xc = x[base + d];
      float a = bias[j] + win[j][0] * wv[j][0] + win[j][1] * wv[j][1]
                        + win[j][2] * wv[j][2] + xc * wv[j][3];
      float sv = a / (1.f + __expf(-a));
      xb[base + d]  = f2bs(xc);
      xcb[base + d] = f2bs(sv);
      win[j][0] = win[j][1]; win[j][1] = win[j][2]; win[j][2] = xc;
    }
  }
}

// ---------------- K2: headwise projections -> P[s][h][b][g][e] (bf16) ----------------
__global__ __launch_bounds__(256) void proj_kernel(
    const short* __restrict__ xb, const short* __restrict__ xcb,
    const short* __restrict__ Wbf, short* __restrict__ P)
{
  const int hg = blockIdx.y;
  const int h = hg >> 2, g = hg & 3;
  const short* A  = (g < 2) ? xcb : xb;           // gi,gf from conv(x); gz,go from x
  const short* Wb = Wbf + (size_t)hg * (DH_ * DH_);
  const int tid = threadIdx.x, w = tid >> 6, l = tid & 63;
  const int l15 = l & 15, lg = l >> 4;
  const int R0 = blockIdx.x * 256 + w * 64;

  for (int mp = 0; mp < 2; ++mp) {
    const int rb0 = R0 + mp * 32;
    floatx4 acc[2][12];
    for (int u = 0; u < 2; ++u)
      for (int nt = 0; nt < 12; ++nt) acc[u][nt] = (floatx4){0.f, 0.f, 0.f, 0.f};
    const short* Ar = A + (size_t)(rb0 + l15) * D_ + h * DH_ + lg * 8;
    const short* Bp = Wb + l15 * DH_ + lg * 8;
    for (int kk = 0; kk < 6; ++kk) {
      short8 a0 = *(const short8*)(Ar + kk * 32);
      short8 a1 = *(const short8*)(Ar + (size_t)16 * D_ + kk * 32);
      for (int nt = 0; nt < 12; ++nt) {
        short8 bf = *(const short8*)(Bp + nt * 16 * DH_ + kk * 32);
        acc[0][nt] = __builtin_amdgcn_mfma_f32_16x16x32_bf16(a0, bf, acc[0][nt], 0, 0, 0);
        acc[1][nt] = __builtin_amdgcn_mfma_f32_16x16x32_bf16(a1, bf, acc[1][nt], 0, 0, 0);
      }
    }
    for (int u = 0; u < 2; ++u) {
      for (int q = 0; q < 4; ++q) {
        int row = rb0 + u * 16 + lg * 4 + q;
        int s = row & (S_ - 1);
        int bb = row >> 12;
        size_t ob = ((size_t)(s * NH_ + h) * B_ + bb) * NTOT_ + g * DH_ + l15;
        for (int nt = 0; nt < 12; ++nt) P[ob + nt * 16] = f2bs(acc[u][nt][q]);
      }
    }
  }
}

// ---------------- K3: sequential sLSTM scan + fused GroupNorm ----------------
// One workgroup per (b,h). R_h kept in VGPRs as MFMA B-fragments.
__global__ __launch_bounds__(512, 2) void scan_kernel(
    const short* __restrict__ P, const float* __restrict__ rk,
    const float* __restrict__ rb, const float* __restrict__ gnw,
    float* __restrict__ out)
{
  const int bid = blockIdx.x;          // 0..31
  const int b = bid >> 2, h = bid & 3;
  const int tid = threadIdx.x;
  const int w = tid >> 6, l = tid & 63;
  const int l15 = l & 15, lg = l >> 4;

  __shared__ short y_lds[DH_];
  __shared__ float raw_lds[NTOT_];
  __shared__ float stats_lds[8];

  // Preload R fragments: wave w owns n-tiles w*6 .. w*6+5
  short8 Bf[6][6];
  {
    const float* Rm = rk + (size_t)h * DH_ * NTOT_;   // Rm[k][n], n = g*192+e
    for (int i = 0; i < 6; ++i) {
      int n = (w * 6 + i) * 16 + l15;
      for (int kk = 0; kk < 6; ++kk) {
        int kb = kk * 32 + lg * 8;
        short8 v;
        for (int j = 0; j < 8; ++j) v[j] = f2bs(Rm[(size_t)(kb + j) * NTOT_ + n]);
        Bf[i][kk] = v;
      }
    }
  }

  float biasv[4] = {0.f, 0.f, 0.f, 0.f};
  float gw = 0.f;
  if (tid < DH_) {
    for (int g = 0; g < 4; ++g) biasv[g] = rb[(g * NH_ + h) * DH_ + tid];
    gw = gnw[h * DH_ + tid];
    y_lds[tid] = 0;
  }

  float c = 0.f, nrm = 0.f, m = 0.f, yprev = 0.f;
  const short* Pb = P + ((size_t)h * B_ + b) * NTOT_;   // + t*24576
  float wxc[4] = {0.f, 0.f, 0.f, 0.f};
  if (tid < DH_) {
    for (int g = 0; g < 4; ++g) wxc[g] = bs2f((unsigned short)Pb[g * DH_ + tid]);
  }
  unsigned short wxn[4] = {0, 0, 0, 0};
  __syncthreads();

  for (int t = 0; t < S_; ++t) {
    // prefetch Wx[t+1] (consumed next iteration; latency hidden under this step)
    if (tid < DH_ && t + 1 < S_) {
      const short* Pt = Pb + (size_t)(t + 1) * (NH_ * B_ * NTOT_);
      for (int g = 0; g < 4; ++g) wxn[g] = (unsigned short)Pt[g * DH_ + tid];
    }
    // finish groupnorm for step t-1 (stats published before last barrier)
    if (t > 0 && tid < DH_) {
      float s0 = stats_lds[0] + stats_lds[2] + stats_lds[4];
      float s1 = stats_lds[1] + stats_lds[3] + stats_lds[5];
      float mean = s0 * (1.f / DH_);
      float var = s1 * (1.f / DH_) - mean * mean;
      float rs = rsqrtf(var + 1e-5f);
      out[((size_t)b * S_ + (t - 1)) * D_ + h * DH_ + tid] = (yprev - mean) * rs * gw;
    }
    // A fragments: broadcast y into all 16 rows (M=1 matvec, rows identical)
    short8 Af[6];
    for (int kk = 0; kk < 6; ++kk)
      Af[kk] = *(const short8*)&y_lds[kk * 32 + lg * 8];
    floatx4 acc[6];
    for (int i = 0; i < 6; ++i) acc[i] = (floatx4){0.f, 0.f, 0.f, 0.f};
    for (int kk = 0; kk < 6; ++kk)
      for (int i = 0; i < 6; ++i)
        acc[i] = __builtin_amdgcn_mfma_f32_16x16x32_bf16(Af[kk], Bf[i][kk], acc[i], 0, 0, 0);
    if (l < 16) {
      for (int i = 0; i < 6; ++i) raw_lds[(w * 6 + i) * 16 + l] = acc[i][0];
    }
    __syncthreads();
    if (tid < DH_) {
      float ir  = wxc[0] + raw_lds[tid] + biasv[0];
      float fr  = wxc[1] + raw_lds[DH_ + tid] + biasv[1];
      float zr  = wxc[2] + raw_lds[2 * DH_ + tid] + biasv[2];
      float orr = wxc[3] + raw_lds[3 * DH_ + tid] + biasv[3];
      float lsf = (fr >= 0.f) ? (0.f - log1pf(__expf(-fr))) : (fr - log1pf(__expf(fr)));
      float lfm = m + lsf;
      float mnew = fmaxf(ir, lfm);
      float ig = __expf(ir - mnew);
      float fg = __expf(lfm - mnew);
      float e2z = __expf(2.f * zr);
      float tz = 1.f - 2.f / (e2z + 1.f);
      c   = fg * c + ig * tz;
      nrm = fg * nrm + ig;
      m = mnew;
      float sg = 1.f / (1.f + __expf(-orr));
      float y = sg * c / nrm;
      yprev = y;
      y_lds[tid] = f2bs(y);
      float ps = y, pq = y * y;
      for (int off = 32; off >= 1; off >>= 1) {
        ps += __shfl_xor(ps, off);
        pq += __shfl_xor(pq, off);
      }
      if (l == 0) { stats_lds[w * 2] = ps; stats_lds[w * 2 + 1] = pq; }
      for (int g = 0; g < 4; ++g) wxc[g] = bs2f(wxn[g]);
    }
    __syncthreads();
  }
  // final groupnorm for t = S-1
  if (tid < DH_) {
    float s0 = stats_lds[0] + stats_lds[2] + stats_lds[4];
    float s1 = stats_lds[1] + stats_lds[3] + stats_lds[5];
    float mean = s0 * (1.f / DH_);
    float var = s1 * (1.f / DH_) - mean * mean;
    float rs = rsqrtf(var + 1e-5f);
    out[((size_t)b * S_ + (S_ - 1)) * D_ + h * DH_ + tid] = (yprev - mean) * rs * gw;
  }
}

extern "C" void kernel_launch(void* const* d_in, const int* in_sizes, int n_in,
                              void* d_out, int out_size, void* d_ws, size_t ws_size,
                              hipStream_t stream) {
  const float* x   = (const float*)d_in[0];
  const float* cw  = (const float*)d_in[1];
  const float* cb  = (const float*)d_in[2];
  const float* wf  = (const float*)d_in[3];
  const float* wi  = (const float*)d_in[4];
  const float* wz  = (const float*)d_in[5];
  const float* wo  = (const float*)d_in[6];
  const float* rk  = (const float*)d_in[7];
  const float* rb  = (const float*)d_in[8];
  const float* gnw = (const float*)d_in[9];
  float* out = (float*)d_out;

  // Workspace: P (bf16 Wx, [S][NH][B][4][DH]) = 201,326,592 B; Wbf = 1,179,648 B
  short* P   = (short*)d_ws;
  short* Wbf = (short*)((char*)d_ws + (size_t)201326592);
  // Reuse d_out (exactly 100,663,296 B) as scratch for bf16 x / conv(x); K3 overwrites it.
  short* xb  = (short*)d_out;
  short* xcb = (short*)((char*)d_out + (size_t)50331648);

  wconv_kernel<<<dim3(2304), 256, 0, stream>>>(wf, wi, wz, wo, Wbf);
  conv_silu_kernel<<<dim3(512), 256, 0, stream>>>(x, cw, cb, xb, xcb);
  proj_kernel<<<dim3(128, 16), 256, 0, stream>>>(xb, xcb, Wbf, P);
  scan_kernel<<<dim3(32), 512, 0, stream>>>(P, rk, rb, gnw, out);
}

// Round 2
// 5830.878 us; speedup vs baseline: 1.0254x; 1.0254x over previous
//
#include <hip/hip_runtime.h>
#include <hip/hip_bf16.h>
#include <math.h>

#define B_ 8
#define S_ 4096
#define D_ 768
#define NH_ 4
#define DH_ 192
#define NTOT_ 768   // 4*DH_

typedef __attribute__((ext_vector_type(8))) short short8;
typedef __attribute__((ext_vector_type(4))) float floatx4;
typedef _Float16 f16;
typedef __attribute__((ext_vector_type(2))) _Float16 h2;

__device__ __forceinline__ short f2bs(float f) {
  union { float f; unsigned u; } v; v.f = f;
  unsigned r = v.u + 0x7FFFu + ((v.u >> 16) & 1u);
  return (short)(r >> 16);
}
__device__ __forceinline__ float bs2f(unsigned short s) {
  union { unsigned u; float f; } v; v.u = ((unsigned)s) << 16;
  return v.f;
}

#if __has_builtin(__builtin_amdgcn_fdot2)
__device__ __forceinline__ float FDOT2(h2 a, h2 b, float c) {
  return __builtin_amdgcn_fdot2(a, b, c, false);
}
#else
__device__ __forceinline__ float FDOT2(h2 a, h2 b, float c) {
  return c + (float)a.x * (float)b.x + (float)a.y * (float)b.y;
}
#endif

template<int CTRL>
__device__ __forceinline__ float qbcast(float x) {
  return __int_as_float(__builtin_amdgcn_mov_dpp(__float_as_int(x), CTRL, 0xf, 0xf, true));
}

// ---------------- K0: weights -> bf16, fragment-friendly [hg][o][d] ----------------
__global__ __launch_bounds__(256) void wconv_kernel(
    const float* __restrict__ wf, const float* __restrict__ wi,
    const float* __restrict__ wz, const float* __restrict__ wo,
    short* __restrict__ Wbf)
{
  int idx = blockIdx.x * 256 + threadIdx.x;      // < 16*36864
  int hg = idx / (DH_ * DH_);
  int r  = idx % (DH_ * DH_);
  int h = hg >> 2, g = hg & 3;
  const float* W = (g == 0) ? wf : (g == 1) ? wi : (g == 2) ? wz : wo;
  Wbf[idx] = f2bs(W[(size_t)h * DH_ * DH_ + r]);
}

// ---------------- K1: depthwise causal conv + SiLU; also bf16 copy of x ----------------
__global__ __launch_bounds__(256) void conv_silu_kernel(
    const float* __restrict__ x, const float* __restrict__ cw, const float* __restrict__ cb,
    short* __restrict__ xb, short* __restrict__ xcb)
{
  const int b  = blockIdx.x / (S_ / 64);
  const int s0 = (blockIdx.x % (S_ / 64)) * 64;
  const int tid = threadIdx.x;
  float wv[3][4], bias[3], win[3][3];
  for (int j = 0; j < 3; ++j) {
    int d = tid + j * 256;
    for (int k = 0; k < 4; ++k) wv[j][k] = cw[d * 4 + k];
    bias[j] = cb[d];
    for (int p = 0; p < 3; ++p) {
      int s = s0 - 3 + p;
      win[j][p] = (s >= 0) ? x[((size_t)b * S_ + s) * D_ + d] : 0.f;
    }
  }
  for (int i = 0; i < 64; ++i) {
    size_t base = ((size_t)b * S_ + (s0 + i)) * D_;
    for (int j = 0; j < 3; ++j) {
      int d = tid + j * 256;
      float xc = x[base + d];
      float a = bias[j] + win[j][0] * wv[j][0] + win[j][1] * wv[j][1]
                        + win[j][2] * wv[j][2] + xc * wv[j][3];
      float sv = a / (1.f + __expf(-a));
      xb[base + d]  = f2bs(xc);
      xcb[base + d] = f2bs(sv);
      win[j][0] = win[j][1]; win[j][1] = win[j][2]; win[j][2] = xc;
    }
  }
}

// ---------------- K2: headwise projections -> P[h][b][s][g*192+e] (bf16) ----------------
__global__ __launch_bounds__(256) void proj_kernel(
    const short* __restrict__ xb, const short* __restrict__ xcb,
    const short* __restrict__ Wbf, short* __restrict__ P)
{
  const int hg = blockIdx.y;
  const int h = hg >> 2, g = hg & 3;
  const short* A  = (g < 2) ? xcb : xb;           // gi,gf from conv(x); gz,go from x
  const short* Wb = Wbf + (size_t)hg * (DH_ * DH_);
  const int tid = threadIdx.x, w = tid >> 6, l = tid & 63;
  const int l15 = l & 15, lg = l >> 4;
  const int R0 = blockIdx.x * 256 + w * 64;

  for (int mp = 0; mp < 2; ++mp) {
    const int rb0 = R0 + mp * 32;
    floatx4 acc[2][12];
    for (int u = 0; u < 2; ++u)
      for (int nt = 0; nt < 12; ++nt) acc[u][nt] = (floatx4){0.f, 0.f, 0.f, 0.f};
    const short* Ar = A + (size_t)(rb0 + l15) * D_ + h * DH_ + lg * 8;
    const short* Bp = Wb + l15 * DH_ + lg * 8;
    for (int kk = 0; kk < 6; ++kk) {
      short8 a0 = *(const short8*)(Ar + kk * 32);
      short8 a1 = *(const short8*)(Ar + (size_t)16 * D_ + kk * 32);
      for (int nt = 0; nt < 12; ++nt) {
        short8 bf = *(const short8*)(Bp + nt * 16 * DH_ + kk * 32);
        acc[0][nt] = __builtin_amdgcn_mfma_f32_16x16x32_bf16(a0, bf, acc[0][nt], 0, 0, 0);
        acc[1][nt] = __builtin_amdgcn_mfma_f32_16x16x32_bf16(a1, bf, acc[1][nt], 0, 0, 0);
      }
    }
    for (int u = 0; u < 2; ++u) {
      for (int q = 0; q < 4; ++q) {
        int row = rb0 + u * 16 + lg * 4 + q;
        int s = row & (S_ - 1);
        int bb = row >> 12;
        size_t ob = (((size_t)h * B_ + bb) * S_ + s) * NTOT_ + g * DH_ + l15;
        for (int nt = 0; nt < 12; ++nt) P[ob + nt * 16] = f2bs(acc[u][nt][q]);
      }
    }
  }
}

// ---------------- K3: sequential sLSTM scan (pure VALU, f16 dot2) ----------------
// One workgroup of 768 threads per (h,b) chain. Thread t owns output
// n = g*192+e with (e,g) = (t>>2, t&3); holds R column (192 f16) in 96 VGPRs.
// After storing y for step t, the first 192 ushorts of the (consumed) P row t
// are overwritten with y (f16) for the later groupnorm pass.
__global__ __launch_bounds__(768) void scan_kernel(
    short* P_, const float* __restrict__ rk, const float* __restrict__ rb)
{
  const int bid = blockIdx.x;      // 0..31: chain (h,b)
  const int h = bid >> 3;
  const int t0 = threadIdx.x;      // 0..767
  const int e = t0 >> 2, g = t0 & 3;

  __shared__ __align__(16) f16 y_lds[2][DH_];

  // R column: rk[h][k][g][e], k = 0..191, packed f16 pairs
  h2 Rr[96];
  {
    const float* Rc = rk + (size_t)h * (DH_ * NTOT_) + g * DH_ + e;
#pragma unroll
    for (int j = 0; j < 96; ++j) {
      float v0 = Rc[(size_t)(2 * j) * NTOT_];
      float v1 = Rc[(size_t)(2 * j + 1) * NTOT_];
      Rr[j] = (h2){(f16)v0, (f16)v1};
    }
  }
  const float biasv = rb[(g * NH_ + h) * DH_ + e];
  if (t0 < DH_) y_lds[0][t0] = (f16)0.f;

  float c = 0.f, nrm = 0.f, m = 0.f;
  short* Pc = P_ + (size_t)bid * S_ * NTOT_;
  const int addr = g * DH_ + e;
  float wxc = bs2f((unsigned short)Pc[addr]);
  __syncthreads();

#pragma unroll 1
  for (int t = 0; t < S_; ++t) {
    unsigned short wxn = 0;
    if (t + 1 < S_) wxn = (unsigned short)Pc[(size_t)(t + 1) * NTOT_ + addr];

    const int cur = t & 1, nxt = cur ^ 1;
    const f16* yb = &y_lds[cur][0];
    float a0 = 0.f, a1 = 0.f, a2 = 0.f, a3 = 0.f;
#pragma unroll
    for (int j = 0; j < 96; j += 4) {
      h2 y0 = *(const h2*)(yb + 2 * j);
      h2 y1 = *(const h2*)(yb + 2 * j + 2);
      h2 y2 = *(const h2*)(yb + 2 * j + 4);
      h2 y3 = *(const h2*)(yb + 2 * j + 6);
      a0 = FDOT2(Rr[j],     y0, a0);
      a1 = FDOT2(Rr[j + 1], y1, a1);
      a2 = FDOT2(Rr[j + 2], y2, a2);
      a3 = FDOT2(Rr[j + 3], y3, a3);
    }
    float raw = wxc + ((a0 + a1) + (a2 + a3)) + biasv;

    // quad broadcast: all 4 lanes of the quad get all 4 gates of element e
    float ir  = qbcast<0x00>(raw);
    float fr  = qbcast<0x55>(raw);
    float zr  = qbcast<0xAA>(raw);
    float orr = qbcast<0xFF>(raw);

    float lsf = fminf(fr, 0.f) - __logf(1.f + __expf(-fabsf(fr)));
    float lfm = m + lsf;
    float mnew = fmaxf(ir, lfm);
    float ig = __expf(ir - mnew);
    float fg = __expf(lfm - mnew);
    float e2z = __expf(2.f * zr);
    float tz = 1.f - 2.f / (e2z + 1.f);
    c   = fg * c + ig * tz;
    nrm = fg * nrm + ig;
    m = mnew;
    float sg = 1.f / (1.f + __expf(-orr));
    float y = sg * c / nrm;

    f16 yh = (f16)y;
    if (g == 0) {
      y_lds[nxt][e] = yh;
      union { f16 h; short s; } uv; uv.h = yh;
      Pc[(size_t)t * NTOT_ + e] = uv.s;     // y history for groupnorm (row already consumed)
    }
    wxc = bs2f(wxn);
    __syncthreads();
  }
}

// ---------------- K4: groupnorm over DH per (h,b,s) row ----------------
__global__ __launch_bounds__(256) void gnorm_kernel(
    const short* __restrict__ yws, const float* __restrict__ gnw,
    float* __restrict__ out)
{
  const int row = blockIdx.x * 4 + (threadIdx.x >> 6);   // (h,b,s), 0..131071
  const int l = threadIdx.x & 63;
  const int h = row >> 15;
  const int b = (row >> 12) & 7;
  const int s = row & (S_ - 1);
  const short* yr = yws + (size_t)row * NTOT_;
  float v[3];
  float su = 0.f, sq = 0.f;
#pragma unroll
  for (int j = 0; j < 3; ++j) {
    unsigned short u = (unsigned short)yr[l + j * 64];
    union { unsigned short u; f16 h; } cv; cv.u = u;
    v[j] = (float)cv.h;
    su += v[j]; sq += v[j] * v[j];
  }
  for (int off = 32; off; off >>= 1) {
    su += __shfl_xor(su, off);
    sq += __shfl_xor(sq, off);
  }
  float mean = su * (1.f / DH_);
  float var = sq * (1.f / DH_) - mean * mean;
  float rs = rsqrtf(var + 1e-5f);
  float* orow = out + ((size_t)b * S_ + s) * D_ + h * DH_;
#pragma unroll
  for (int j = 0; j < 3; ++j)
    orow[l + j * 64] = (v[j] - mean) * rs * gnw[h * DH_ + l + j * 64];
}

extern "C" void kernel_launch(void* const* d_in, const int* in_sizes, int n_in,
                              void* d_out, int out_size, void* d_ws, size_t ws_size,
                              hipStream_t stream) {
  const float* x   = (const float*)d_in[0];
  const float* cw  = (const float*)d_in[1];
  const float* cb  = (const float*)d_in[2];
  const float* wf  = (const float*)d_in[3];
  const float* wi  = (const float*)d_in[4];
  const float* wz  = (const float*)d_in[5];
  const float* wo  = (const float*)d_in[6];
  const float* rk  = (const float*)d_in[7];
  const float* rb  = (const float*)d_in[8];
  const float* gnw = (const float*)d_in[9];
  float* out = (float*)d_out;

  // Workspace: P (bf16 Wx, [h][b][s][768]) = 201,326,592 B; Wbf = 1,179,648 B
  short* P   = (short*)d_ws;
  short* Wbf = (short*)((char*)d_ws + (size_t)201326592);
  // Reuse d_out (100,663,296 B) as scratch for bf16 x / conv(x); gnorm overwrites it.
  short* xb  = (short*)d_out;
  short* xcb = (short*)((char*)d_out + (size_t)50331648);

  wconv_kernel<<<dim3(2304), 256, 0, stream>>>(wf, wi, wz, wo, Wbf);
  conv_silu_kernel<<<dim3(512), 256, 0, stream>>>(x, cw, cb, xb, xcb);
  proj_kernel<<<dim3(128, 16), 256, 0, stream>>>(xb, xcb, Wbf, P);
  scan_kernel<<<dim3(32), 768, 0, stream>>>(P, rk, rb);
  gnorm_kernel<<<dim3(32768), 256, 0, stream>>>(P, gnw, out);
}

// Round 3
// 5579.826 us; speedup vs baseline: 1.0716x; 1.0450x over previous
//
#include <hip/hip_runtime.h>
#include <hip/hip_bf16.h>
#include <math.h>

#define B_ 8
#define S_ 4096
#define D_ 768
#define NH_ 4
#define DH_ 192
#define NTOT_ 768   // 4*DH_

typedef __attribute__((ext_vector_type(8))) short short8;
typedef __attribute__((ext_vector_type(4))) float floatx4;
typedef __attribute__((ext_vector_type(4))) short short4v;
typedef _Float16 f16;
typedef __attribute__((ext_vector_type(2))) _Float16 h2;
typedef __attribute__((ext_vector_type(8))) _Float16 h8;

__device__ __forceinline__ short f2bs(float f) {
  union { float f; unsigned u; } v; v.f = f;
  unsigned r = v.u + 0x7FFFu + ((v.u >> 16) & 1u);
  return (short)(r >> 16);
}
__device__ __forceinline__ float bs2f(unsigned short s) {
  union { unsigned u; float f; } v; v.u = ((unsigned)s) << 16;
  return v.f;
}

#if __has_builtin(__builtin_amdgcn_fdot2)
__device__ __forceinline__ float FDOT2(h2 a, h2 b, float c) {
  return __builtin_amdgcn_fdot2(a, b, c, false);
}
#else
__device__ __forceinline__ float FDOT2(h2 a, h2 b, float c) {
  return c + (float)a.x * (float)b.x + (float)a.y * (float)b.y;
}
#endif

// quad-perm DPP helper (register-only cross-lane within quad)
template<int CTRL>
__device__ __forceinline__ float qperm(float x) {
  return __int_as_float(__builtin_amdgcn_mov_dpp(__float_as_int(x), CTRL, 0xf, 0xf, true));
}

// ---------------- K0: weights -> bf16, fragment-friendly [hg][o][d] ----------------
__global__ __launch_bounds__(256) void wconv_kernel(
    const float* __restrict__ wf, const float* __restrict__ wi,
    const float* __restrict__ wz, const float* __restrict__ wo,
    short* __restrict__ Wbf)
{
  int idx = blockIdx.x * 256 + threadIdx.x;      // < 16*36864
  int hg = idx / (DH_ * DH_);
  int r  = idx % (DH_ * DH_);
  int h = hg >> 2, g = hg & 3;
  const float* W = (g == 0) ? wf : (g == 1) ? wi : (g == 2) ? wz : wo;
  Wbf[idx] = f2bs(W[(size_t)h * DH_ * DH_ + r]);
}

// ---------------- K1: depthwise causal conv + SiLU; also bf16 copy of x ----------------
__global__ __launch_bounds__(256) void conv_silu_kernel(
    const float* __restrict__ x, const float* __restrict__ cw, const float* __restrict__ cb,
    short* __restrict__ xb, short* __restrict__ xcb)
{
  const int b  = blockIdx.x / (S_ / 64);
  const int s0 = (blockIdx.x % (S_ / 64)) * 64;
  const int tid = threadIdx.x;
  float wv[3][4], bias[3], win[3][3];
  for (int j = 0; j < 3; ++j) {
    int d = tid + j * 256;
    for (int k = 0; k < 4; ++k) wv[j][k] = cw[d * 4 + k];
    bias[j] = cb[d];
    for (int p = 0; p < 3; ++p) {
      int s = s0 - 3 + p;
      win[j][p] = (s >= 0) ? x[((size_t)b * S_ + s) * D_ + d] : 0.f;
    }
  }
  for (int i = 0; i < 64; ++i) {
    size_t base = ((size_t)b * S_ + (s0 + i)) * D_;
    for (int j = 0; j < 3; ++j) {
      int d = tid + j * 256;
      float xc = x[base + d];
      float a = bias[j] + win[j][0] * wv[j][0] + win[j][1] * wv[j][1]
                        + win[j][2] * wv[j][2] + xc * wv[j][3];
      float sv = a / (1.f + __expf(-a));
      xb[base + d]  = f2bs(xc);
      xcb[base + d] = f2bs(sv);
      win[j][0] = win[j][1]; win[j][1] = win[j][2]; win[j][2] = xc;
    }
  }
}

// ---------------- K2: headwise projections -> P[h][b][s][e*4+g] (bf16) ----------------
__global__ __launch_bounds__(256) void proj_kernel(
    const short* __restrict__ xb, const short* __restrict__ xcb,
    const short* __restrict__ Wbf, short* __restrict__ P)
{
  const int hg = blockIdx.y;
  const int h = hg >> 2, g = hg & 3;
  const short* A  = (g < 2) ? xcb : xb;           // gi,gf from conv(x); gz,go from x
  const short* Wb = Wbf + (size_t)hg * (DH_ * DH_);
  const int tid = threadIdx.x, w = tid >> 6, l = tid & 63;
  const int l15 = l & 15, lg = l >> 4;
  const int R0 = blockIdx.x * 256 + w * 64;

  for (int mp = 0; mp < 2; ++mp) {
    const int rb0 = R0 + mp * 32;
    floatx4 acc[2][12];
    for (int u = 0; u < 2; ++u)
      for (int nt = 0; nt < 12; ++nt) acc[u][nt] = (floatx4){0.f, 0.f, 0.f, 0.f};
    const short* Ar = A + (size_t)(rb0 + l15) * D_ + h * DH_ + lg * 8;
    const short* Bp = Wb + l15 * DH_ + lg * 8;
    for (int kk = 0; kk < 6; ++kk) {
      short8 a0 = *(const short8*)(Ar + kk * 32);
      short8 a1 = *(const short8*)(Ar + (size_t)16 * D_ + kk * 32);
      for (int nt = 0; nt < 12; ++nt) {
        short8 bf = *(const short8*)(Bp + nt * 16 * DH_ + kk * 32);
        acc[0][nt] = __builtin_amdgcn_mfma_f32_16x16x32_bf16(a0, bf, acc[0][nt], 0, 0, 0);
        acc[1][nt] = __builtin_amdgcn_mfma_f32_16x16x32_bf16(a1, bf, acc[1][nt], 0, 0, 0);
      }
    }
    for (int u = 0; u < 2; ++u) {
      for (int q = 0; q < 4; ++q) {
        int row = rb0 + u * 16 + lg * 4 + q;
        int s = row & (S_ - 1);
        int bb = row >> 12;
        // packed gate-interleaved layout: column (e)*4 + g, e = l15 + nt*16
        size_t ob = (((size_t)h * B_ + bb) * S_ + s) * NTOT_ + l15 * 4 + g;
        for (int nt = 0; nt < 12; ++nt) P[ob + nt * 64] = f2bs(acc[u][nt][q]);
      }
    }
  }
}

// ---------------- K3: sequential sLSTM scan (VALU dot2, quad k-split) ----------------
// One workgroup of 768 threads per (h,b) chain. Lane (e,q) = (t0>>2, t0&3):
// owns k-slice [48q,48q+48) for ALL 4 gate columns of element e.
// Per step: 6x ds_read_b128 of y slice -> 96 fdot2 -> 8 DPP quad-butterfly adds
// -> full gate math per lane (4x quad-redundant, register-only) -> y write.
// y history (f16) stored into first 192 ushorts of the consumed P row.
__global__ __launch_bounds__(768) void scan_kernel(
    short* P_, const float* __restrict__ rk, const float* __restrict__ rb)
{
  const int bid = blockIdx.x;      // 0..31: chain; h = bid>>3, b = bid&7
  const int h = bid >> 3;
  const int t0 = threadIdx.x;      // 0..767
  const int e = t0 >> 2, q = t0 & 3;

  __shared__ __align__(16) f16 y_lds[2][DH_];

  // Rr[g][j] = (R[48q+2j][g][e], R[48q+2j+1][g][e]) as f16 pair
  h2 Rr[4][24];
  {
    const float* Rh = rk + (size_t)h * (DH_ * NTOT_);
#pragma unroll
    for (int j = 0; j < 24; ++j) {
      const int k0 = 48 * q + 2 * j;
#pragma unroll
      for (int g = 0; g < 4; ++g) {
        float v0 = Rh[((size_t)k0 * 4 + g) * DH_ + e];
        float v1 = Rh[((size_t)(k0 + 1) * 4 + g) * DH_ + e];
        Rr[g][j] = (h2){(f16)v0, (f16)v1};
      }
    }
  }
  float biasv[4];
#pragma unroll
  for (int g = 0; g < 4; ++g) biasv[g] = rb[(g * NH_ + h) * DH_ + e];

  if (t0 < DH_) y_lds[0][t0] = (f16)0.f;

  float c = 0.f, nrm = 0.f, m = 0.f;
  short* Pc = P_ + (size_t)bid * S_ * NTOT_;
  short4v wxc = *(const short4v*)(Pc + e * 4);
  __syncthreads();

#pragma unroll 1
  for (int t = 0; t < S_; ++t) {
    short4v wxn = {};
    if (t + 1 < S_) wxn = *(const short4v*)(Pc + (size_t)(t + 1) * NTOT_ + e * 4);

    const f16* yb = &y_lds[t & 1][q * 48];
    float a0 = 0.f, a1 = 0.f, a2 = 0.f, a3 = 0.f;
#pragma unroll
    for (int i = 0; i < 6; ++i) {
      h8 ch = ((const h8*)yb)[i];
#pragma unroll
      for (int u = 0; u < 4; ++u) {
        h2 yp = (h2){ch[2 * u], ch[2 * u + 1]};
        const int j = i * 4 + u;
        a0 = FDOT2(Rr[0][j], yp, a0);
        a1 = FDOT2(Rr[1][j], yp, a1);
        a2 = FDOT2(Rr[2][j], yp, a2);
        a3 = FDOT2(Rr[3][j], yp, a3);
      }
    }
    // quad butterfly: sum partials over the 4 k-slices (register-only)
    a0 += qperm<0xB1>(a0);  a0 += qperm<0x4E>(a0);
    a1 += qperm<0xB1>(a1);  a1 += qperm<0x4E>(a1);
    a2 += qperm<0xB1>(a2);  a2 += qperm<0x4E>(a2);
    a3 += qperm<0xB1>(a3);  a3 += qperm<0x4E>(a3);

    float ir  = bs2f((unsigned short)wxc[0]) + a0 + biasv[0];
    float fr  = bs2f((unsigned short)wxc[1]) + a1 + biasv[1];
    float zr  = bs2f((unsigned short)wxc[2]) + a2 + biasv[2];
    float orr = bs2f((unsigned short)wxc[3]) + a3 + biasv[3];

    float lsf = fminf(fr, 0.f) - __logf(1.f + __expf(-fabsf(fr)));
    float lfm = m + lsf;
    float mnew = fmaxf(ir, lfm);
    float ig = __expf(ir - mnew);
    float fg = __expf(lfm - mnew);
    float e2z = __expf(2.f * zr);
    float tz = 1.f - 2.f / (e2z + 1.f);
    c   = fg * c + ig * tz;
    nrm = fg * nrm + ig;
    m = mnew;
    float sg = 1.f / (1.f + __expf(-orr));
    float y = sg * c / nrm;

    f16 yh = (f16)y;
    if (q == 0) {
      y_lds[(t & 1) ^ 1][e] = yh;
      union { f16 hh; short ss; } uv; uv.hh = yh;
      Pc[(size_t)t * NTOT_ + e] = uv.ss;   // y history (row already consumed)
    }
    wxc = wxn;
    __syncthreads();
  }
}

// ---------------- K4: groupnorm over DH per (h,b,s) row ----------------
__global__ __launch_bounds__(256) void gnorm_kernel(
    const short* __restrict__ yws, const float* __restrict__ gnw,
    float* __restrict__ out)
{
  const int row = blockIdx.x * 4 + (threadIdx.x >> 6);   // (h,b,s), 0..131071
  const int l = threadIdx.x & 63;
  const int h = row >> 15;
  const int b = (row >> 12) & 7;
  const int s = row & (S_ - 1);
  const short* yr = yws + (size_t)row * NTOT_;
  float v[3];
  float su = 0.f, sq = 0.f;
#pragma unroll
  for (int j = 0; j < 3; ++j) {
    unsigned short u = (unsigned short)yr[l + j * 64];
    union { unsigned short u; f16 h; } cv; cv.u = u;
    v[j] = (float)cv.h;
    su += v[j]; sq += v[j] * v[j];
  }
  for (int off = 32; off; off >>= 1) {
    su += __shfl_xor(su, off);
    sq += __shfl_xor(sq, off);
  }
  float mean = su * (1.f / DH_);
  float var = sq * (1.f / DH_) - mean * mean;
  float rs = rsqrtf(var + 1e-5f);
  float* orow = out + ((size_t)b * S_ + s) * D_ + h * DH_;
#pragma unroll
  for (int j = 0; j < 3; ++j)
    orow[l + j * 64] = (v[j] - mean) * rs * gnw[h * DH_ + l + j * 64];
}

extern "C" void kernel_launch(void* const* d_in, const int* in_sizes, int n_in,
                              void* d_out, int out_size, void* d_ws, size_t ws_size,
                              hipStream_t stream) {
  const float* x   = (const float*)d_in[0];
  const float* cw  = (const float*)d_in[1];
  const float* cb  = (const float*)d_in[2];
  const float* wf  = (const float*)d_in[3];
  const float* wi  = (const float*)d_in[4];
  const float* wz  = (const float*)d_in[5];
  const float* wo  = (const float*)d_in[6];
  const float* rk  = (const float*)d_in[7];
  const float* rb  = (const float*)d_in[8];
  const float* gnw = (const float*)d_in[9];
  float* out = (float*)d_out;

  // Workspace: P (bf16 Wx, [h][b][s][768]) = 201,326,592 B; Wbf = 1,179,648 B
  short* P   = (short*)d_ws;
  short* Wbf = (short*)((char*)d_ws + (size_t)201326592);
  // Reuse d_out (100,663,296 B) as scratch for bf16 x / conv(x); gnorm overwrites it.
  short* xb  = (short*)d_out;
  short* xcb = (short*)((char*)d_out + (size_t)50331648);

  wconv_kernel<<<dim3(2304), 256, 0, stream>>>(wf, wi, wz, wo, Wbf);
  conv_silu_kernel<<<dim3(512), 256, 0, stream>>>(x, cw, cb, xb, xcb);
  proj_kernel<<<dim3(128, 16), 256, 0, stream>>>(xb, xcb, Wbf, P);
  scan_kernel<<<dim3(32), 768, 0, stream>>>(P, rk, rb);
  gnorm_kernel<<<dim3(32768), 256, 0, stream>>>(P, gnw, out);
}

// Round 5
// 5576.976 us; speedup vs baseline: 1.0721x; 1.0005x over previous
//
#include <hip/hip_runtime.h>
#include <hip/hip_bf16.h>
#include <math.h>

#define B_ 8
#define S_ 4096
#define D_ 768
#define NH_ 4
#define DH_ 192
#define NTOT_ 768   // 4*DH_

typedef __attribute__((ext_vector_type(8))) short short8;
typedef __attribute__((ext_vector_type(4))) float floatx4;
typedef __attribute__((ext_vector_type(4))) short short4v;
typedef _Float16 f16;
typedef __attribute__((ext_vector_type(2))) _Float16 h2;
typedef __attribute__((ext_vector_type(8))) _Float16 h8;

__device__ __forceinline__ short f2bs(float f) {
  union { float f; unsigned u; } v; v.f = f;
  unsigned r = v.u + 0x7FFFu + ((v.u >> 16) & 1u);
  return (short)(r >> 16);
}
__device__ __forceinline__ float bs2f(unsigned short s) {
  union { unsigned u; float f; } v; v.u = ((unsigned)s) << 16;
  return v.f;
}

// f32-accumulating packed-f16 dot: v_dot2_f32_f16 when available, else the
// (float)cast form which ISel turns into v_fma_mix_f32 pairs. BOTH accumulate
// in f32 — the f16-accumulate variant (R4) is numerically dead in this recurrence.
#if __has_builtin(__builtin_amdgcn_fdot2)
__device__ __forceinline__ float FDOT2(h2 a, h2 b, float c) {
  return __builtin_amdgcn_fdot2(a, b, c, false);
}
#else
__device__ __forceinline__ float FDOT2(h2 a, h2 b, float c) {
  return c + (float)a.x * (float)b.x + (float)a.y * (float)b.y;
}
#endif

// quad-perm DPP helper (register-only cross-lane within quad)
template<int CTRL>
__device__ __forceinline__ float qperm(float x) {
  return __int_as_float(__builtin_amdgcn_mov_dpp(__float_as_int(x), CTRL, 0xf, 0xf, true));
}

// ---------------- K0: weights -> bf16, fragment-friendly [hg][o][d] ----------------
__global__ __launch_bounds__(256) void wconv_kernel(
    const float* __restrict__ wf, const float* __restrict__ wi,
    const float* __restrict__ wz, const float* __restrict__ wo,
    short* __restrict__ Wbf)
{
  int idx = blockIdx.x * 256 + threadIdx.x;      // < 16*36864
  int hg = idx / (DH_ * DH_);
  int r  = idx % (DH_ * DH_);
  int h = hg >> 2, g = hg & 3;
  const float* W = (g == 0) ? wf : (g == 1) ? wi : (g == 2) ? wz : wo;
  Wbf[idx] = f2bs(W[(size_t)h * DH_ * DH_ + r]);
}

// ---------------- K1: depthwise causal conv + SiLU; also bf16 copy of x ----------------
__global__ __launch_bounds__(256) void conv_silu_kernel(
    const float* __restrict__ x, const float* __restrict__ cw, const float* __restrict__ cb,
    short* __restrict__ xb, short* __restrict__ xcb)
{
  const int b  = blockIdx.x / (S_ / 64);
  const int s0 = (blockIdx.x % (S_ / 64)) * 64;
  const int tid = threadIdx.x;
  float wv[3][4], bias[3], win[3][3];
  for (int j = 0; j < 3; ++j) {
    int d = tid + j * 256;
    for (int k = 0; k < 4; ++k) wv[j][k] = cw[d * 4 + k];
    bias[j] = cb[d];
    for (int p = 0; p < 3; ++p) {
      int s = s0 - 3 + p;
      win[j][p] = (s >= 0) ? x[((size_t)b * S_ + s) * D_ + d] : 0.f;
    }
  }
  for (int i = 0; i < 64; ++i) {
    size_t base = ((size_t)b * S_ + (s0 + i)) * D_;
    for (int j = 0; j < 3; ++j) {
      int d = tid + j * 256;
      float xc = x[base + d];
      float a = bias[j] + win[j][0] * wv[j][0] + win[j][1] * wv[j][1]
                        + win[j][2] * wv[j][2] + xc * wv[j][3];
      float sv = a / (1.f + __expf(-a));
      xb[base + d]  = f2bs(xc);
      xcb[base + d] = f2bs(sv);
      win[j][0] = win[j][1]; win[j][1] = win[j][2]; win[j][2] = xc;
    }
  }
}

// ---------------- K2: headwise projections -> P[h][b][s][e*4+g] (bf16) ----------------
__global__ __launch_bounds__(256) void proj_kernel(
    const short* __restrict__ xb, const short* __restrict__ xcb,
    const short* __restrict__ Wbf, short* __restrict__ P)
{
  const int hg = blockIdx.y;
  const int h = hg >> 2, g = hg & 3;
  const short* A  = (g < 2) ? xcb : xb;           // gi,gf from conv(x); gz,go from x
  const short* Wb = Wbf + (size_t)hg * (DH_ * DH_);
  const int tid = threadIdx.x, w = tid >> 6, l = tid & 63;
  const int l15 = l & 15, lg = l >> 4;
  const int R0 = blockIdx.x * 256 + w * 64;

  for (int mp = 0; mp < 2; ++mp) {
    const int rb0 = R0 + mp * 32;
    floatx4 acc[2][12];
    for (int u = 0; u < 2; ++u)
      for (int nt = 0; nt < 12; ++nt) acc[u][nt] = (floatx4){0.f, 0.f, 0.f, 0.f};
    const short* Ar = A + (size_t)(rb0 + l15) * D_ + h * DH_ + lg * 8;
    const short* Bp = Wb + l15 * DH_ + lg * 8;
    for (int kk = 0; kk < 6; ++kk) {
      short8 a0 = *(const short8*)(Ar + kk * 32);
      short8 a1 = *(const short8*)(Ar + (size_t)16 * D_ + kk * 32);
      for (int nt = 0; nt < 12; ++nt) {
        short8 bf = *(const short8*)(Bp + nt * 16 * DH_ + kk * 32);
        acc[0][nt] = __builtin_amdgcn_mfma_f32_16x16x32_bf16(a0, bf, acc[0][nt], 0, 0, 0);
        acc[1][nt] = __builtin_amdgcn_mfma_f32_16x16x32_bf16(a1, bf, acc[1][nt], 0, 0, 0);
      }
    }
    for (int u = 0; u < 2; ++u) {
      for (int q = 0; q < 4; ++q) {
        int row = rb0 + u * 16 + lg * 4 + q;
        int s = row & (S_ - 1);
        int bb = row >> 12;
        // packed gate-interleaved layout: column (e)*4 + g, e = l15 + nt*16
        size_t ob = (((size_t)h * B_ + bb) * S_ + s) * NTOT_ + l15 * 4 + g;
        for (int nt = 0; nt < 12; ++nt) P[ob + nt * 64] = f2bs(acc[u][nt][q]);
      }
    }
  }
}

// ---------------- K3: sequential sLSTM scan (VALU dot2, quad k-split) ----------------
// One workgroup of 768 threads per (h,b) chain. Lane (e,q) = (t0>>2, t0&3):
// owns k-slice [48q,48q+48) for ALL 4 gate columns of element e.
// __launch_bounds__(768, 3): grid is 32 WGs -> exactly 1 WG/CU; cap VGPRs at
// ~170 so the 96-reg Rr array stays architectural (R3's 84-VGPR build shuttled it).
__global__ __launch_bounds__(768, 3) void scan_kernel(
    short* P_, const float* __restrict__ rk, const float* __restrict__ rb)
{
  const int bid = blockIdx.x;      // 0..31: chain; h = bid>>3, b = bid&7
  const int h = bid >> 3;
  const int t0 = threadIdx.x;      // 0..767
  const int e = t0 >> 2, q = t0 & 3;

  __shared__ __align__(16) f16 y_lds[2][DH_];

  // Rr[g][j] = (R[48q+2j][g][e], R[48q+2j+1][g][e]) as f16 pair  (96 VGPRs)
  h2 Rr[4][24];
  {
    const float* Rh = rk + (size_t)h * (DH_ * NTOT_);
#pragma unroll
    for (int j = 0; j < 24; ++j) {
      const int k0 = 48 * q + 2 * j;
#pragma unroll
      for (int g = 0; g < 4; ++g) {
        float v0 = Rh[((size_t)k0 * 4 + g) * DH_ + e];
        float v1 = Rh[((size_t)(k0 + 1) * 4 + g) * DH_ + e];
        Rr[g][j] = (h2){(f16)v0, (f16)v1};
      }
    }
  }
  float biasv[4];
#pragma unroll
  for (int g = 0; g < 4; ++g) biasv[g] = rb[(g * NH_ + h) * DH_ + e];

  if (t0 < DH_) y_lds[0][t0] = (f16)0.f;

  float c = 0.f, nrm = 0.f, m = 0.f;
  short* Pc = P_ + (size_t)bid * S_ * NTOT_;
  short4v wxc = *(const short4v*)(Pc + e * 4);
  __syncthreads();

#pragma unroll 1
  for (int t = 0; t < S_; ++t) {
    short4v wxn = {};
    if (t + 1 < S_) wxn = *(const short4v*)(Pc + (size_t)(t + 1) * NTOT_ + e * 4);

    const f16* yb = &y_lds[t & 1][q * 48];
    float a0 = 0.f, a1 = 0.f, a2 = 0.f, a3 = 0.f;
#pragma unroll
    for (int i = 0; i < 6; ++i) {
      h8 ch = ((const h8*)yb)[i];
#pragma unroll
      for (int u = 0; u < 4; ++u) {
        h2 yp = (h2){ch[2 * u], ch[2 * u + 1]};
        const int j = i * 4 + u;
        a0 = FDOT2(Rr[0][j], yp, a0);
        a1 = FDOT2(Rr[1][j], yp, a1);
        a2 = FDOT2(Rr[2][j], yp, a2);
        a3 = FDOT2(Rr[3][j], yp, a3);
      }
    }
    // quad butterfly: sum partials over the 4 k-slices (register-only)
    a0 += qperm<0xB1>(a0);  a0 += qperm<0x4E>(a0);
    a1 += qperm<0xB1>(a1);  a1 += qperm<0x4E>(a1);
    a2 += qperm<0xB1>(a2);  a2 += qperm<0x4E>(a2);
    a3 += qperm<0xB1>(a3);  a3 += qperm<0x4E>(a3);

    float ir  = bs2f((unsigned short)wxc[0]) + a0 + biasv[0];
    float fr  = bs2f((unsigned short)wxc[1]) + a1 + biasv[1];
    float zr  = bs2f((unsigned short)wxc[2]) + a2 + biasv[2];
    float orr = bs2f((unsigned short)wxc[3]) + a3 + biasv[3];

    float lsf = fminf(fr, 0.f) - __logf(1.f + __expf(-fabsf(fr)));
    float lfm = m + lsf;
    float mnew = fmaxf(ir, lfm);
    float ig = __expf(ir - mnew);
    float fg = __expf(lfm - mnew);
    float e2z = __expf(2.f * zr);
    float tz = 1.f - 2.f / (e2z + 1.f);
    c   = fg * c + ig * tz;
    nrm = fg * nrm + ig;
    m = mnew;
    float sg = 1.f / (1.f + __expf(-orr));
    float y = sg * c / nrm;

    f16 yh = (f16)y;
    if (q == 0) {
      y_lds[(t & 1) ^ 1][e] = yh;
      union { f16 hh; short ss; } uv; uv.hh = yh;
      Pc[(size_t)t * NTOT_ + e] = uv.ss;   // y history (row already consumed)
    }
    wxc = wxn;
    __syncthreads();
  }
}

// ---------------- K4: groupnorm over DH per (h,b,s) row ----------------
__global__ __launch_bounds__(256) void gnorm_kernel(
    const short* __restrict__ yws, const float* __restrict__ gnw,
    float* __restrict__ out)
{
  const int row = blockIdx.x * 4 + (threadIdx.x >> 6);   // (h,b,s), 0..131071
  const int l = threadIdx.x & 63;
  const int h = row >> 15;
  const int b = (row >> 12) & 7;
  const int s = row & (S_ - 1);
  const short* yr = yws + (size_t)row * NTOT_;
  float v[3];
  float su = 0.f, sq = 0.f;
#pragma unroll
  for (int j = 0; j < 3; ++j) {
    unsigned short u = (unsigned short)yr[l + j * 64];
    union { unsigned short u; f16 h; } cv; cv.u = u;
    v[j] = (float)cv.h;
    su += v[j]; sq += v[j] * v[j];
  }
  for (int off = 32; off; off >>= 1) {
    su += __shfl_xor(su, off);
    sq += __shfl_xor(sq, off);
  }
  float mean = su * (1.f / DH_);
  float var = sq * (1.f / DH_) - mean * mean;
  float rs = rsqrtf(var + 1e-5f);
  float* orow = out + ((size_t)b * S_ + s) * D_ + h * DH_;
#pragma unroll
  for (int j = 0; j < 3; ++j)
    orow[l + j * 64] = (v[j] - mean) * rs * gnw[h * DH_ + l + j * 64];
}

extern "C" void kernel_launch(void* const* d_in, const int* in_sizes, int n_in,
                              void* d_out, int out_size, void* d_ws, size_t ws_size,
                              hipStream_t stream) {
  const float* x   = (const float*)d_in[0];
  const float* cw  = (const float*)d_in[1];
  const float* cb  = (const float*)d_in[2];
  const float* wf  = (const float*)d_in[3];
  const float* wi  = (const float*)d_in[4];
  const float* wz  = (const float*)d_in[5];
  const float* wo  = (const float*)d_in[6];
  const float* rk  = (const float*)d_in[7];
  const float* rb  = (const float*)d_in[8];
  const float* gnw = (const float*)d_in[9];
  float* out = (float*)d_out;

  // Workspace: P (bf16 Wx, [h][b][s][768]) = 201,326,592 B; Wbf = 1,179,648 B
  short* P   = (short*)d_ws;
  short* Wbf = (short*)((char*)d_ws + (size_t)201326592);
  // Reuse d_out (100,663,296 B) as scratch for bf16 x / conv(x); gnorm overwrites it.
  short* xb  = (short*)d_out;
  short* xcb = (short*)((char*)d_out + (size_t)50331648);

  wconv_kernel<<<dim3(2304), 256, 0, stream>>>(wf, wi, wz, wo, Wbf);
  conv_silu_kernel<<<dim3(512), 256, 0, stream>>>(x, cw, cb, xb, xcb);
  proj_kernel<<<dim3(128, 16), 256, 0, stream>>>(xb, xcb, Wbf, P);
  scan_kernel<<<dim3(32), 768, 0, stream>>>(P, rk, rb);
  gnorm_kernel<<<dim3(32768), 256, 0, stream>>>(P, gnw, out);
}